// Round 5
// baseline (329.701 us; speedup 1.0000x reference)
//
#include <hip/hip_runtime.h>

#define BB 32
#define TT 128
#define II 256
#define HH 256
#define OO 128
#define FWID 512  // H + I

// d_ws: u64 slots[2][BB][HH] (parity, batch, row) = 128 KB.
// Slot = (stamp<<32)|float_bits(h); step s consumes stamp>=s from parity s&1,
// publishes stamp s+1 into parity (s+1)&1. Agent-scope relaxed (no fences);
// protocol proven on HW (R2/R3/R5/R8 of prior session + R13). u64 atomics
// cannot tear. Overwrite safety: publish(s+1) happens only after this block's
// gather(s), so a slot's stamp-(s-1) readers have all retired — unchanged.
//
// R17 (from R16: sc0-L2 fast path DEAD even with claimed co-location -> all
// fast/claim machinery deleted; plain launch kept). New structure: TEMPORAL
// DUAL-BATCH. 256 blocks = 16 pairs (p,p+16) x 16 slices of 16 rows; 32-lane
// row-groups. Each thread carries TWO independent recurrences (F_A, F_B; W/L/G
// shared — batch-independent). Per step: P_A -> gatherA(wv0) -> dot_A ->
// publish_A -> U_A -> P_B -> gatherB(wv1) -> dot_B -> publish_B -> U_B.
// Batch B's compute fills batch A's relay wait and vice versa:
// tau ~ max(2x compute, relay RT) instead of compute + relay.
// Reduces: 4x DPP row_ror (16-lane) + 1x ds_swizzle xor-16 = 32-lane sum.
// Predicted: kernel 95-140us, VALUBusy 55-75%, VGPR ~180-220.

typedef unsigned long long u64;
typedef float f32x2 __attribute__((ext_vector_type(2)));

__device__ __forceinline__ f32x2 mk2(float a, float b) { f32x2 r; r.x = a; r.y = b; return r; }

__device__ __forceinline__ f32x2 pk_fma(f32x2 a, f32x2 b, f32x2 c) {
    f32x2 d;
    asm("v_pk_fma_f32 %0, %1, %2, %3" : "=v"(d) : "v"(a), "v"(b), "v"(c));
    return d;
}
__device__ __forceinline__ f32x2 pk_mul(f32x2 a, f32x2 b) {
    f32x2 d;
    asm("v_pk_mul_f32 %0, %1, %2" : "=v"(d) : "v"(a), "v"(b));
    return d;
}
__device__ __forceinline__ f32x2 pk_add(f32x2 a, f32x2 b) {
    f32x2 d;
    asm("v_pk_add_f32 %0, %1, %2" : "=v"(d) : "v"(a), "v"(b));
    return d;
}

template<int CTRL>
__device__ __forceinline__ float dpp_add(float x) {
    int t = __builtin_amdgcn_update_dpp(0, __float_as_int(x), CTRL, 0xF, 0xF, true);
    return x + __int_as_float(t);
}
// 32-lane butterfly sum: 4 DPP row_ror levels (16-lane rows) + xor-16 swizzle.
// Result valid in all 32 lanes of the group. Paired version hides swizzle lgkm.
__device__ __forceinline__ void red32_pair(float& a, float& b) {
    a = dpp_add<0x128>(a); b = dpp_add<0x128>(b);
    a = dpp_add<0x124>(a); b = dpp_add<0x124>(b);
    a = dpp_add<0x122>(a); b = dpp_add<0x122>(b);
    a = dpp_add<0x121>(a); b = dpp_add<0x121>(b);
    int ta = __builtin_amdgcn_ds_swizzle(__float_as_int(a), 0x401F);  // xor 16
    int tb = __builtin_amdgcn_ds_swizzle(__float_as_int(b), 0x401F);
    a += __int_as_float(ta); b += __int_as_float(tb);
}
__device__ __forceinline__ float red32(float a) {
    a = dpp_add<0x128>(a); a = dpp_add<0x124>(a);
    a = dpp_add<0x122>(a); a = dpp_add<0x121>(a);
    a += __int_as_float(__builtin_amdgcn_ds_swizzle(__float_as_int(a), 0x401F));
    return a;
}

__device__ __forceinline__ u64 slot_ld(const u64* p) {
    return __hip_atomic_load(p, __ATOMIC_RELAXED, __HIP_MEMORY_SCOPE_AGENT);
}

// One wave gathers 256 rows of one batch (4 slots/lane, issued concurrently),
// stages h to LDS (ds_write_b128), release-stores an LDS flag.
__device__ __forceinline__ void gather_to_lds(const u64* base, int lane, unsigned us,
                                              float* dst, int* flag, int fval) {
    const u64* p = base + 4 * lane;
    u64 a, b, c, d;
    for (;;) {
        a = slot_ld(p);
        b = slot_ld(p + 1);
        c = slot_ld(p + 2);
        d = slot_ld(p + 3);
        bool ok = ((unsigned)(a >> 32) >= us) & ((unsigned)(b >> 32) >= us) &
                  ((unsigned)(c >> 32) >= us) & ((unsigned)(d >> 32) >= us);
        if (__all(ok)) break;
    }
    float4 hv;
    hv.x = __uint_as_float((unsigned)a);
    hv.y = __uint_as_float((unsigned)b);
    hv.z = __uint_as_float((unsigned)c);
    hv.w = __uint_as_float((unsigned)d);
    *reinterpret_cast<float4*>(dst + 4 * lane) = hv;
    if (lane == 0)  // release drains the wave's ds_write before the flag
        __hip_atomic_store(flag, fval, __ATOMIC_RELEASE, __HIP_MEMORY_SCOPE_WORKGROUP);
}

__global__ __launch_bounds__(512, 2)
void stpn_kernel(const float* __restrict__ x,      // (B,T,I)
                 const float* __restrict__ wlam,   // (H,FWID)
                 const float* __restrict__ wgam,   // (H,FWID)
                 const float* __restrict__ w,      // (H,FWID)
                 const float* __restrict__ bias,   // (H)
                 const float* __restrict__ wout,   // (O,H)
                 const float* __restrict__ bout,   // (O)
                 float* __restrict__ out,          // tag(4096) | h_T(8192) | F_T
                 u64* __restrict__ slots)
{
    __shared__ __align__(16) float lh[2][2][HH];   // [parity][sel][row]
    __shared__ int lflag[4];                       // [parity*2 + sel]

    const int tid  = threadIdx.x;
    const int bk   = blockIdx.x;
    const int p    = bk & 15;        // batch pair -> batches p, p+16
    const int sl   = bk >> 4;        // row slice 0..15 (16 rows each)
    const int bA   = p;
    const int bB   = p + 16;
    const int wv   = tid >> 6;       // 0..7
    const int lane = tid & 63;
    const int g    = tid >> 5;       // 32-lane group 0..15 == row-within-slice
    const int i    = tid & 31;       // lane within group
    const int r    = sl * 16 + g;

    if (tid < 4) lflag[tid] = 0;

    // Per-lane f-chunks of row r: f = 128*k + 4*i + c, k=0..3; pair j=2k+pp
    // covers c=2pp,2pp+1. k<2 x-part, k>=2 h-part. W/L/G batch-independent.
    f32x2 W2[8], Lm2[8], G2[8], FA[8], FB[8];
    {
        const float4* wr = reinterpret_cast<const float4*>(w    + (size_t)r * FWID);
        const float4* lr = reinterpret_cast<const float4*>(wlam + (size_t)r * FWID);
        const float4* gr = reinterpret_cast<const float4*>(wgam + (size_t)r * FWID);
#pragma unroll
        for (int k = 0; k < 4; ++k) {
            float4 t;
            t = wr[k * 32 + i]; W2[2*k]  = mk2(t.x, t.y); W2[2*k+1]  = mk2(t.z, t.w);
            t = lr[k * 32 + i]; Lm2[2*k] = mk2(t.x, t.y); Lm2[2*k+1] = mk2(t.z, t.w);
            t = gr[k * 32 + i]; G2[2*k]  = mk2(t.x, t.y); G2[2*k+1]  = mk2(t.z, t.w);
            FA[2*k] = mk2(0.f, 0.f); FA[2*k+1] = mk2(0.f, 0.f);
            FB[2*k] = mk2(0.f, 0.f); FB[2*k+1] = mk2(0.f, 0.f);
        }
    }
    const float bj = bias[r];
    float hlA = 0.f, hlB = 0.f;

    // preload x(0) for both batches: x-part f = 128k+4i+c, k=0,1
    f32x2 XA[4], XB[4];
    {
        const float4* xa4 = reinterpret_cast<const float4*>(x + (size_t)bA * TT * II);
        const float4* xb4 = reinterpret_cast<const float4*>(x + (size_t)bB * TT * II);
        float4 t0 = xa4[i], t1 = xa4[32 + i];
        XA[0] = mk2(t0.x, t0.y); XA[1] = mk2(t0.z, t0.w);
        XA[2] = mk2(t1.x, t1.y); XA[3] = mk2(t1.z, t1.w);
        t0 = xb4[i]; t1 = xb4[32 + i];
        XB[0] = mk2(t0.x, t0.y); XB[1] = mk2(t0.z, t0.w);
        XB[2] = mk2(t1.x, t1.y); XB[3] = mk2(t1.z, t1.w);
    }

    __syncthreads();   // lflag init visible

    for (int s = 0; s < TT; ++s) {
        const int par = s & 1;

        // ================= batch A =================
        {
            f32x2 tw[4];
            f32x2 dx2 = mk2(0.f, 0.f), nv2 = mk2(0.f, 0.f);
#pragma unroll
            for (int j = 0; j < 4; ++j) {              // x-part pairs
                f32x2 t = pk_add(W2[j], FA[j]);
                dx2 = pk_fma(XA[j], t, dx2);
                nv2 = pk_fma(t, t, nv2);
            }
#pragma unroll
            for (int j = 0; j < 4; ++j) {              // h-part pairs
                tw[j] = pk_add(W2[4 + j], FA[4 + j]);
                nv2 = pk_fma(tw[j], tw[j], nv2);
            }
            float dxs = dx2.x + dx2.y;
            float nrm = nv2.x + nv2.y;
            red32_pair(dxs, nrm);
            const float invn = __builtin_amdgcn_rsqf(nrm);
            const f32x2 invn2 = mk2(invn, invn);
            const float dxb = dxs + bj;
#pragma unroll
            for (int j = 0; j < 8; ++j) FA[j] = pk_mul(Lm2[j], pk_mul(FA[j], invn2));

            if (wv == 0) {
                gather_to_lds(slots + ((size_t)par * BB + bA) * HH, lane,
                              (unsigned)s, lh[par][0], &lflag[par * 2 + 0], s + 1);
            }
            while (__hip_atomic_load(&lflag[par * 2 + 0], __ATOMIC_ACQUIRE,
                                     __HIP_MEMORY_SCOPE_WORKGROUP) <= s) {}
            const float4* lh4 = reinterpret_cast<const float4*>(lh[par][0]);
            float4 h0 = lh4[i], h1 = lh4[32 + i];
            f32x2 H2[4];
            H2[0] = mk2(h0.x, h0.y); H2[1] = mk2(h0.z, h0.w);
            H2[2] = mk2(h1.x, h1.y); H2[3] = mk2(h1.z, h1.w);

            f32x2 a2 = pk_mul(H2[0], tw[0]);
            f32x2 b2 = pk_mul(H2[1], tw[1]);
            a2 = pk_fma(H2[2], tw[2], a2);
            b2 = pk_fma(H2[3], tw[3], b2);
            f32x2 c2 = pk_add(a2, b2);
            float dh = red32(c2.x + c2.y);

            const float e = __expf(2.0f * (dxb + dh));
            const float h = (1.0f - 2.0f * __builtin_amdgcn_rcpf(e + 1.0f)) * invn;
            hlA = h;

            if (i == 0) {
                __hip_atomic_store(slots + ((size_t)(par ^ 1) * BB + bA) * HH + r,
                                   ((u64)(unsigned)(s + 1) << 32) | (unsigned)__float_as_uint(h),
                                   __ATOMIC_RELAXED, __HIP_MEMORY_SCOPE_AGENT);
            }

            // x_A(s+1) prefetch: issue now, consume after U_A
            float4 t0n, t1n;
            const bool pf = (s + 1 < TT);
            if (pf) {
                const float4* xn = reinterpret_cast<const float4*>(x + ((size_t)bA * TT + (s + 1)) * II);
                t0n = xn[i]; t1n = xn[32 + i];
            }
            const f32x2 h2v = mk2(h, h);
#pragma unroll
            for (int j = 0; j < 4; ++j)
                FA[j] = pk_fma(pk_mul(XA[j], G2[j]), h2v, FA[j]);
#pragma unroll
            for (int j = 0; j < 4; ++j)
                FA[4 + j] = pk_fma(pk_mul(G2[4 + j], H2[j]), h2v, FA[4 + j]);
            if (pf) {
                XA[0] = mk2(t0n.x, t0n.y); XA[1] = mk2(t0n.z, t0n.w);
                XA[2] = mk2(t1n.x, t1n.y); XA[3] = mk2(t1n.z, t1n.w);
            }
        }

        // ================= batch B =================
        {
            f32x2 tw[4];
            f32x2 dx2 = mk2(0.f, 0.f), nv2 = mk2(0.f, 0.f);
#pragma unroll
            for (int j = 0; j < 4; ++j) {
                f32x2 t = pk_add(W2[j], FB[j]);
                dx2 = pk_fma(XB[j], t, dx2);
                nv2 = pk_fma(t, t, nv2);
            }
#pragma unroll
            for (int j = 0; j < 4; ++j) {
                tw[j] = pk_add(W2[4 + j], FB[4 + j]);
                nv2 = pk_fma(tw[j], tw[j], nv2);
            }
            float dxs = dx2.x + dx2.y;
            float nrm = nv2.x + nv2.y;
            red32_pair(dxs, nrm);
            const float invn = __builtin_amdgcn_rsqf(nrm);
            const f32x2 invn2 = mk2(invn, invn);
            const float dxb = dxs + bj;
#pragma unroll
            for (int j = 0; j < 8; ++j) FB[j] = pk_mul(Lm2[j], pk_mul(FB[j], invn2));

            if (wv == 1) {
                gather_to_lds(slots + ((size_t)par * BB + bB) * HH, lane,
                              (unsigned)s, lh[par][1], &lflag[par * 2 + 1], s + 1);
            }
            while (__hip_atomic_load(&lflag[par * 2 + 1], __ATOMIC_ACQUIRE,
                                     __HIP_MEMORY_SCOPE_WORKGROUP) <= s) {}
            const float4* lh4 = reinterpret_cast<const float4*>(lh[par][1]);
            float4 h0 = lh4[i], h1 = lh4[32 + i];
            f32x2 H2[4];
            H2[0] = mk2(h0.x, h0.y); H2[1] = mk2(h0.z, h0.w);
            H2[2] = mk2(h1.x, h1.y); H2[3] = mk2(h1.z, h1.w);

            f32x2 a2 = pk_mul(H2[0], tw[0]);
            f32x2 b2 = pk_mul(H2[1], tw[1]);
            a2 = pk_fma(H2[2], tw[2], a2);
            b2 = pk_fma(H2[3], tw[3], b2);
            f32x2 c2 = pk_add(a2, b2);
            float dh = red32(c2.x + c2.y);

            const float e = __expf(2.0f * (dxb + dh));
            const float h = (1.0f - 2.0f * __builtin_amdgcn_rcpf(e + 1.0f)) * invn;
            hlB = h;

            if (i == 0) {
                __hip_atomic_store(slots + ((size_t)(par ^ 1) * BB + bB) * HH + r,
                                   ((u64)(unsigned)(s + 1) << 32) | (unsigned)__float_as_uint(h),
                                   __ATOMIC_RELAXED, __HIP_MEMORY_SCOPE_AGENT);
            }

            float4 t0n, t1n;
            const bool pf = (s + 1 < TT);
            if (pf) {
                const float4* xn = reinterpret_cast<const float4*>(x + ((size_t)bB * TT + (s + 1)) * II);
                t0n = xn[i]; t1n = xn[32 + i];
            }
            const f32x2 h2v = mk2(h, h);
#pragma unroll
            for (int j = 0; j < 4; ++j)
                FB[j] = pk_fma(pk_mul(XB[j], G2[j]), h2v, FB[j]);
#pragma unroll
            for (int j = 0; j < 4; ++j)
                FB[4 + j] = pk_fma(pk_mul(G2[4 + j], H2[j]), h2v, FB[4 + j]);
            if (pf) {
                XB[0] = mk2(t0n.x, t0n.y); XB[1] = mk2(t0n.z, t0n.w);
                XB[2] = mk2(t1n.x, t1n.y); XB[3] = mk2(t1n.z, t1n.w);
            }
        }
    }

    // ---- epilogue: F_T, h_T (both batches) ----
    {
        float4* foA = reinterpret_cast<float4*>(out + 12288 + ((size_t)bA * HH + r) * FWID);
        float4* foB = reinterpret_cast<float4*>(out + 12288 + ((size_t)bB * HH + r) * FWID);
#pragma unroll
        for (int k = 0; k < 4; ++k) {
            float4 v;
            v.x = FA[2*k].x; v.y = FA[2*k].y; v.z = FA[2*k+1].x; v.w = FA[2*k+1].y;
            foA[k * 32 + i] = v;
            v.x = FB[2*k].x; v.y = FB[2*k].y; v.z = FB[2*k+1].x; v.w = FB[2*k+1].y;
            foB[k * 32 + i] = v;
        }
    }
    if (i == 0) {
        out[4096 + (size_t)bA * HH + r] = hlA;
        out[4096 + (size_t)bB * HH + r] = hlB;
    }

    // tag_space: sl==0 blocks (one per pair) gather final h (stamp TT, parity 0)
    if (sl == 0) {
        if (wv == 0) {
            gather_to_lds(slots + ((size_t)(TT & 1) * BB + bA) * HH, lane,
                          (unsigned)TT, lh[0][0], &lflag[0], TT + 1);
        }
        if (wv == 1) {
            gather_to_lds(slots + ((size_t)(TT & 1) * BB + bB) * HH, lane,
                          (unsigned)TT, lh[0][1], &lflag[1], TT + 1);
        }
        if (tid < OO) {
            while (__hip_atomic_load(&lflag[0], __ATOMIC_ACQUIRE,
                                     __HIP_MEMORY_SCOPE_WORKGROUP) <= TT) {}
            const float* hv = lh[0][0];
            float acc = bout[tid];
            const float* wo = wout + (size_t)tid * HH;
#pragma unroll 4
            for (int jj = 0; jj < HH; ++jj) acc = fmaf(wo[jj], hv[jj], acc);
            out[(size_t)bA * OO + tid] = acc;
        } else if (tid < 2 * OO) {
            const int o = tid - OO;
            while (__hip_atomic_load(&lflag[1], __ATOMIC_ACQUIRE,
                                     __HIP_MEMORY_SCOPE_WORKGROUP) <= TT) {}
            const float* hv = lh[0][1];
            float acc = bout[o];
            const float* wo = wout + (size_t)o * HH;
#pragma unroll 4
            for (int jj = 0; jj < HH; ++jj) acc = fmaf(wo[jj], hv[jj], acc);
            out[(size_t)bB * OO + o] = acc;
        }
    }
}

extern "C" void kernel_launch(void* const* d_in, const int* in_sizes, int n_in,
                              void* d_out, int out_size, void* d_ws, size_t ws_size,
                              hipStream_t stream) {
    (void)in_sizes; (void)n_in; (void)out_size; (void)ws_size;
    const float* x    = (const float*)d_in[0];
    const float* wlam = (const float*)d_in[1];
    const float* wgam = (const float*)d_in[2];
    const float* w    = (const float*)d_in[3];
    const float* bias = (const float*)d_in[4];
    const float* wout = (const float*)d_in[5];
    const float* bout = (const float*)d_in[6];
    float* out = (float*)d_out;

    u64* slots = (u64*)d_ws;

    // stamp 0 + h = 0.0 is exactly what step 0 consumes
    hipMemsetAsync(d_ws, 0, 2ull * BB * HH * 8ull, stream);

    // Plain launch: grid 256 == co-residency capacity (8 waves/block, 1
    // block/CU x 256 CUs); no grid-wide sync primitive is used. R14 measured:
    // plain launch cut the harness-rocprof gap 79us -> 28us vs cooperative.
    hipLaunchKernelGGL(stpn_kernel, dim3(256), dim3(512), 0, stream,
                       x, wlam, wgam, w, bias, wout, bout, out, slots);
}

// Round 6
// 242.751 us; speedup vs baseline: 1.3582x; 1.3582x over previous
//
#include <hip/hip_runtime.h>

#define BB 32
#define TT 128
#define II 256
#define HH 256
#define OO 128
#define FWID 512  // H + I

// d_ws: u64 slots[2][BB][HH] (parity, batch, row) = 128 KB.
// Slot = (stamp<<32)|float_bits(h); step s consumes stamp>=s from parity s&1,
// publishes stamp s+1 into parity (s+1)&1. Agent-scope relaxed (no fences);
// protocol proven on HW. Overwrite safety: publish(s+1) only after this
// block's gather(s) => all stamp-(s-1) readers retired. u64 cannot tear.
//
// R18 = R13 (best kernel, 187us) + relay micro-attacks:
//  - REVERTED R17 dual-batch (339us: intra-thread serialization can't overlap
//    the two relay chains; straggler group doubled 8->16).
//  - REVERTED all sc0/L2 fast-path machinery (R14/R15/R16: sc0 store+load via
//    XCD-local L2 is not consumer-visible on gfx950 even with claimed
//    co-location; three escalating attempts all timed out).
//  - Depth-2 pipelined slot polling: one 4-load round always in flight;
//    discovery quantum ~L/2 instead of L (~-300 cy/step).
//  - s_setprio(1) around gather (wave 0): wins SIMD0 issue vs flag-spinner.
//  - s_sleep(1) in consumer flag spins: frees SIMD issue during waits.
//  - Paired DPP reduce for (dxs, nrm): halves reduce dep-chain latency.
//  - Plain launch (R14: coop replay costs ~40-75us) + 128KB memset only.
// Predicted: kernel 165-180us, harness 200-225, VALUBusy 38-48%.

typedef unsigned long long u64;
typedef float f32x2 __attribute__((ext_vector_type(2)));

__device__ __forceinline__ f32x2 mk2(float a, float b) { f32x2 r; r.x = a; r.y = b; return r; }

__device__ __forceinline__ f32x2 pk_fma(f32x2 a, f32x2 b, f32x2 c) {
    f32x2 d;
    asm("v_pk_fma_f32 %0, %1, %2, %3" : "=v"(d) : "v"(a), "v"(b), "v"(c));
    return d;
}
__device__ __forceinline__ f32x2 pk_mul(f32x2 a, f32x2 b) {
    f32x2 d;
    asm("v_pk_mul_f32 %0, %1, %2" : "=v"(d) : "v"(a), "v"(b));
    return d;
}
__device__ __forceinline__ f32x2 pk_add(f32x2 a, f32x2 b) {
    f32x2 d;
    asm("v_pk_add_f32 %0, %1, %2" : "=v"(d) : "v"(a), "v"(b));
    return d;
}

template<int CTRL>
__device__ __forceinline__ float dpp_add(float x) {
    int t = __builtin_amdgcn_update_dpp(0, __float_as_int(x), CTRL, 0xF, 0xF, true);
    return x + __int_as_float(t);
}
// 16-lane butterfly sum via DPP row_ror; result valid in all 16 lanes.
__device__ __forceinline__ float row16_sum(float x) {
    x = dpp_add<0x128>(x);  // row_ror:8
    x = dpp_add<0x124>(x);  // row_ror:4
    x = dpp_add<0x122>(x);  // row_ror:2
    x = dpp_add<0x121>(x);  // row_ror:1
    return x;
}
// Paired version: interleaves the two dep chains (half the serial latency).
__device__ __forceinline__ void row16_sum2(float& a, float& b) {
    a = dpp_add<0x128>(a); b = dpp_add<0x128>(b);
    a = dpp_add<0x124>(a); b = dpp_add<0x124>(b);
    a = dpp_add<0x122>(a); b = dpp_add<0x122>(b);
    a = dpp_add<0x121>(a); b = dpp_add<0x121>(b);
}

__device__ __forceinline__ u64 slot_ld(const u64* p) {
    return __hip_atomic_load(p, __ATOMIC_RELAXED, __HIP_MEMORY_SCOPE_AGENT);
}

// One wave gathers 256 rows of one batch (4 slots/lane), stages h to LDS
// (ds_write_b128), release-stores an LDS flag. Depth-2 pipelined poll: while
// checking round k, round k+1's loads are already in flight, so the check
// needs only vmcnt(4) and discovery quantum ~= latency/2.
__device__ __forceinline__ void gather_to_lds(const u64* base, int lane, unsigned us,
                                              float* dst, int* flag, int fval) {
    const u64* p = base + 4 * lane;
    u64 a, b, c, d;
    {
        u64 a0 = slot_ld(p), b0 = slot_ld(p + 1), c0 = slot_ld(p + 2), d0 = slot_ld(p + 3);
        for (;;) {
            u64 a1 = slot_ld(p), b1 = slot_ld(p + 1), c1 = slot_ld(p + 2), d1 = slot_ld(p + 3);
            bool ok0 = ((unsigned)(a0 >> 32) >= us) & ((unsigned)(b0 >> 32) >= us) &
                       ((unsigned)(c0 >> 32) >= us) & ((unsigned)(d0 >> 32) >= us);
            if (__all(ok0)) { a = a0; b = b0; c = c0; d = d0; break; }
            a0 = slot_ld(p); b0 = slot_ld(p + 1); c0 = slot_ld(p + 2); d0 = slot_ld(p + 3);
            bool ok1 = ((unsigned)(a1 >> 32) >= us) & ((unsigned)(b1 >> 32) >= us) &
                       ((unsigned)(c1 >> 32) >= us) & ((unsigned)(d1 >> 32) >= us);
            if (__all(ok1)) { a = a1; b = b1; c = c1; d = d1; break; }
        }
    }
    float4 hv;
    hv.x = __uint_as_float((unsigned)a);
    hv.y = __uint_as_float((unsigned)b);
    hv.z = __uint_as_float((unsigned)c);
    hv.w = __uint_as_float((unsigned)d);
    *reinterpret_cast<float4*>(dst + 4 * lane) = hv;
    if (lane == 0)  // release drains the wave's ds_write before the flag
        __hip_atomic_store(flag, fval, __ATOMIC_RELEASE, __HIP_MEMORY_SCOPE_WORKGROUP);
}

__global__ __launch_bounds__(512, 2)
void stpn_kernel(const float* __restrict__ x,      // (B,T,I)
                 const float* __restrict__ wlam,   // (H,FWID)
                 const float* __restrict__ wgam,   // (H,FWID)
                 const float* __restrict__ w,      // (H,FWID)
                 const float* __restrict__ bias,   // (H)
                 const float* __restrict__ wout,   // (O,H)
                 const float* __restrict__ bout,   // (O)
                 float* __restrict__ out,          // tag(4096) | h_T(8192) | F_T
                 u64* __restrict__ slots)
{
    __shared__ __align__(16) float lh[2][HH];      // [parity][row]
    __shared__ int lflag[2];                       // [parity]

    const int tid  = threadIdx.x;
    const int bk   = blockIdx.x;
    const int b    = bk & 31;        // batch
    const int sl   = bk >> 5;        // row slice 0..7 (32 rows each)
    const int wv   = tid >> 6;       // 0..7
    const int lane = tid & 63;
    const int g    = tid >> 4;       // 16-lane group 0..31 == row-within-slice
    const int i    = tid & 15;       // lane within group
    const int r    = sl * 32 + (g & 31);

    if (tid < 2) lflag[tid] = 0;

    // Per-lane f-chunks of row r: f = 64*k + 4*i + c, pair j = 2k+p covers c=2p,2p+1
    // (k<4 x-part, k>=4 h-part)
    f32x2 W2[16], Lm2[16], G2[16], F2[16];
    {
        const float4* wr = reinterpret_cast<const float4*>(w    + (size_t)r * FWID);
        const float4* lr = reinterpret_cast<const float4*>(wlam + (size_t)r * FWID);
        const float4* gr = reinterpret_cast<const float4*>(wgam + (size_t)r * FWID);
#pragma unroll
        for (int k = 0; k < 8; ++k) {
            float4 t;
            t = wr[k * 16 + i]; W2[2*k]  = mk2(t.x, t.y); W2[2*k+1]  = mk2(t.z, t.w);
            t = lr[k * 16 + i]; Lm2[2*k] = mk2(t.x, t.y); Lm2[2*k+1] = mk2(t.z, t.w);
            t = gr[k * 16 + i]; G2[2*k]  = mk2(t.x, t.y); G2[2*k+1]  = mk2(t.z, t.w);
            F2[2*k] = mk2(0.f, 0.f); F2[2*k+1] = mk2(0.f, 0.f);
        }
    }
    const float bj = bias[r];
    float hl = 0.f;

    // preload x(0)
    float4 px0, px1, px2, px3;
    {
        const float4* xb4 = reinterpret_cast<const float4*>(x + (size_t)b * TT * II);
        px0 = xb4[i]; px1 = xb4[16 + i]; px2 = xb4[32 + i]; px3 = xb4[48 + i];
    }

    __syncthreads();   // lflag init visible

    for (int s = 0; s < TT; ++s) {
        const int par = s & 1;

        f32x2 X2[8];
        X2[0] = mk2(px0.x, px0.y); X2[1] = mk2(px0.z, px0.w);
        X2[2] = mk2(px1.x, px1.y); X2[3] = mk2(px1.z, px1.w);
        X2[4] = mk2(px2.x, px2.y); X2[5] = mk2(px2.z, px2.w);
        X2[6] = mk2(px3.x, px3.y); X2[7] = mk2(px3.z, px3.w);

        // ---- Phase P: independent of h(s), runs before the gather ----
        f32x2 tw2[8];                                  // h-part tw, kept for dot_h
        f32x2 dx2 = mk2(0.f, 0.f), nv2 = mk2(0.f, 0.f);
#pragma unroll
        for (int j = 0; j < 8; ++j) {                  // x-part pairs
            f32x2 t = pk_add(W2[j], F2[j]);
            dx2 = pk_fma(X2[j], t, dx2);
            nv2 = pk_fma(t, t, nv2);
        }
#pragma unroll
        for (int j = 0; j < 8; ++j) {                  // h-part pairs
            tw2[j] = pk_add(W2[8 + j], F2[8 + j]);
            nv2 = pk_fma(tw2[j], tw2[j], nv2);
        }
        float dxs = dx2.x + dx2.y;
        float nrm = nv2.x + nv2.y;
        row16_sum2(dxs, nrm);
        const float invn = __builtin_amdgcn_rsqf(nrm);   // eps 1e-16 negligible, nrm = O(1)
        const f32x2 invn2 = mk2(invn, invn);
        const float dxb = dxs + bj;

        // F decay (h-independent)
#pragma unroll
        for (int j = 0; j < 16; ++j) F2[j] = pk_mul(Lm2[j], pk_mul(F2[j], invn2));

        // ---- gather (wave 0, pipelined after Phase P; prio-boosted) ----
        if (wv == 0) {
            __builtin_amdgcn_s_setprio(1);
            gather_to_lds(slots + ((size_t)par * BB + b) * HH, lane,
                          (unsigned)s, lh[par], &lflag[par], s + 1);
            __builtin_amdgcn_s_setprio(0);
        }

        // ---- Phase W: LDS flag spin (sleep frees SIMD issue), consume h ----
        while (__hip_atomic_load(&lflag[par], __ATOMIC_ACQUIRE, __HIP_MEMORY_SCOPE_WORKGROUP) <= s) {
            __builtin_amdgcn_s_sleep(1);
        }
        const float4* lh4 = reinterpret_cast<const float4*>(lh[par]);
        float4 ha = lh4[i], hb = lh4[16 + i], hc = lh4[32 + i], hd = lh4[48 + i];
        f32x2 H2[8];
        H2[0] = mk2(ha.x, ha.y); H2[1] = mk2(ha.z, ha.w);
        H2[2] = mk2(hb.x, hb.y); H2[3] = mk2(hb.z, hb.w);
        H2[4] = mk2(hc.x, hc.y); H2[5] = mk2(hc.z, hc.w);
        H2[6] = mk2(hd.x, hd.y); H2[7] = mk2(hd.z, hd.w);

        // dot_h: 2 packed chains of 4 + combine (short dep depth)
        f32x2 a2 = pk_mul(H2[0], tw2[0]);
        f32x2 b2 = pk_mul(H2[1], tw2[1]);
        a2 = pk_fma(H2[2], tw2[2], a2);
        b2 = pk_fma(H2[3], tw2[3], b2);
        a2 = pk_fma(H2[4], tw2[4], a2);
        b2 = pk_fma(H2[5], tw2[5], b2);
        a2 = pk_fma(H2[6], tw2[6], a2);
        b2 = pk_fma(H2[7], tw2[7], b2);
        f32x2 c2 = pk_add(a2, b2);
        float dh = c2.x + c2.y;
        dh = row16_sum(dh);

        const float e = __expf(2.0f * (dxb + dh));
        const float h = (1.0f - 2.0f * __builtin_amdgcn_rcpf(e + 1.0f)) * invn;
        hl = h;

        // publish ASAP (relaxed agent store, no fence)
        if (i == 0) {
            __hip_atomic_store(slots + ((size_t)(par ^ 1) * BB + b) * HH + r,
                               ((u64)(unsigned)(s + 1) << 32) | (unsigned)__float_as_uint(h),
                               __ATOMIC_RELAXED, __HIP_MEMORY_SCOPE_AGENT);
        }

        // x(s+1) prefetch: in flight under Phase U, consumed at next loop top
        if (s + 1 < TT) {
            const float4* xn = reinterpret_cast<const float4*>(x + ((size_t)b * TT + (s + 1)) * II);
            px0 = xn[i]; px1 = xn[16 + i]; px2 = xn[32 + i]; px3 = xn[48 + i];
        }

        // ---- Phase U: F += (gamma*input)*h ----
        const f32x2 h2v = mk2(h, h);
#pragma unroll
        for (int j = 0; j < 8; ++j)
            F2[j] = pk_fma(pk_mul(X2[j], G2[j]), h2v, F2[j]);
#pragma unroll
        for (int j = 0; j < 8; ++j)
            F2[8 + j] = pk_fma(pk_mul(G2[8 + j], H2[j]), h2v, F2[8 + j]);
    }

    // ---- epilogue: F_T, h_T ----
    {
        float4* fo = reinterpret_cast<float4*>(out + 12288 + ((size_t)b * HH + r) * FWID);
#pragma unroll
        for (int k = 0; k < 8; ++k) {
            float4 v;
            v.x = F2[2*k].x; v.y = F2[2*k].y; v.z = F2[2*k+1].x; v.w = F2[2*k+1].y;
            fo[k * 16 + i] = v;
        }
    }
    if (i == 0) out[4096 + (size_t)b * HH + r] = hl;

    // tag_space: sl==0 blocks (one per batch) gather final h (stamp TT, parity 0)
    if (sl == 0) {
        if (wv == 0) {
            gather_to_lds(slots + ((size_t)(TT & 1) * BB + b) * HH, lane,
                          (unsigned)TT, lh[0], &lflag[0], TT + 1);
        }
        while (__hip_atomic_load(&lflag[0], __ATOMIC_ACQUIRE, __HIP_MEMORY_SCOPE_WORKGROUP) <= TT) {
            __builtin_amdgcn_s_sleep(1);
        }
        if (tid < OO) {
            const float* hv = lh[0];
            float acc = bout[tid];
            const float* wo = wout + (size_t)tid * HH;
#pragma unroll 4
            for (int jj = 0; jj < HH; ++jj) acc = fmaf(wo[jj], hv[jj], acc);
            out[(size_t)b * OO + tid] = acc;
        }
    }
}

extern "C" void kernel_launch(void* const* d_in, const int* in_sizes, int n_in,
                              void* d_out, int out_size, void* d_ws, size_t ws_size,
                              hipStream_t stream) {
    (void)in_sizes; (void)n_in; (void)out_size; (void)ws_size;
    const float* x    = (const float*)d_in[0];
    const float* wlam = (const float*)d_in[1];
    const float* wgam = (const float*)d_in[2];
    const float* w    = (const float*)d_in[3];
    const float* bias = (const float*)d_in[4];
    const float* wout = (const float*)d_in[5];
    const float* bout = (const float*)d_in[6];
    float* out = (float*)d_out;

    u64* slots = (u64*)d_ws;

    // stamp 0 + h = 0.0 is exactly what step 0 consumes
    hipMemsetAsync(d_ws, 0, 2ull * BB * HH * 8ull, stream);

    // Plain launch: grid 256 <= co-residency capacity (launch_bounds(512,2));
    // no grid-wide sync primitive is used. R14 measured: plain launch cut the
    // harness-rocprof gap 79us -> 28us vs cooperative.
    hipLaunchKernelGGL(stpn_kernel, dim3(256), dim3(512), 0, stream,
                       x, wlam, wgam, w, bias, wout, bout, out, slots);
}